// Round 16
// baseline (297.337 us; speedup 1.0000x reference)
//
#include <hip/hip_runtime.h>

typedef unsigned short u16;
typedef unsigned int u32;
typedef u16 u16x4 __attribute__((ext_vector_type(4)));
typedef u16 u16x8 __attribute__((ext_vector_type(8)));
typedef float f32x4 __attribute__((ext_vector_type(4)));
typedef __bf16 bf16x8 __attribute__((ext_vector_type(8)));
typedef _Float16 f16x4 __attribute__((ext_vector_type(4)));
typedef _Float16 f16x8 __attribute__((ext_vector_type(8)));

#define DD 2048
#define SCALE_ATTN 0.08838834764831845f
#define DELTA 0.005f

// async global->LDS, 16B per lane, wave-uniform LDS base (HW: base + lane*16)
#define GL16(g, l)                                                              \
  __builtin_amdgcn_global_load_lds((const __attribute__((address_space(1))) u32*)(g), \
                                   (__attribute__((address_space(3))) u32*)(l), 16, 0, 0)

__device__ __forceinline__ u16 f2bf(float f) {
  u32 u = __float_as_uint(f);
  u32 r = (u + 0x7FFFu + ((u >> 16) & 1u)) >> 16;
  return (u16)r;
}
__device__ __forceinline__ float bf2f(u16 h) { return __uint_as_float(((u32)h) << 16); }

// ---------------- prep (single launch): y=0 cvt_x + rope tables; y=1..3
// W_{q,k,v} -> WT16 fp16 + WT32 fp32; y=4: Wo -> BoT bf16 ----------------
__global__ void k_prep(const float* __restrict__ x, _Float16* __restrict__ xf,
                       float* __restrict__ cosT, float* __restrict__ sinT,
                       const float* __restrict__ Wq, const float* __restrict__ Wk,
                       const float* __restrict__ Wv, const float* __restrict__ Wo,
                       _Float16* __restrict__ Wq16, _Float16* __restrict__ Wk16,
                       _Float16* __restrict__ Wv16, float* __restrict__ Wq32,
                       float* __restrict__ Wk32, float* __restrict__ Wv32,
                       u16* __restrict__ BoT) {
  __shared__ float tile[32][33];
  int y = blockIdx.y;
  if (y == 0) {
    int gi = blockIdx.x * 256 + threadIdx.x;
    int i = gi * 4;
    float4 v = *(const float4*)&x[i];
    f16x4 o = {(_Float16)v.x, (_Float16)v.y, (_Float16)v.z, (_Float16)v.w};
    *(f16x4*)&xf[i] = o;
    if (gi < 131072) {  // 2048*64 table entries
      int s = gi >> 6, j = gi & 63;
      float e = (float)(2 * j) / 128.0f;
      float inv = 1.0f / powf(10000.0f, e);
      float fr = (float)s * inv;
      cosT[gi] = cosf(fr);
      sinT[gi] = sinf(fr);
    }
    return;
  }
  int m = y - 1;  // 0..3
  const float* W = m == 0 ? Wq : (m == 1 ? Wk : (m == 2 ? Wv : Wo));
  int bk = blockIdx.x & 63, bn = blockIdx.x >> 6;
  int c = threadIdx.x & 31, r0 = threadIdx.x >> 5;
#pragma unroll
  for (int i = 0; i < 4; ++i) {
    int r = r0 + i * 8;
    tile[r][c] = W[(size_t)(bk * 32 + r) * DD + bn * 32 + c];
  }
  __syncthreads();
  if (m < 3) {
    _Float16* WT16 = m == 0 ? Wq16 : (m == 1 ? Wk16 : Wv16);
    float* WT32 = m == 0 ? Wq32 : (m == 1 ? Wk32 : Wv32);
#pragma unroll
    for (int i = 0; i < 4; ++i) {
      int r = r0 + i * 8;
      float v = tile[c][r];  // = W[bk*32+c][bn*32+r]
      size_t o = (size_t)(bn * 32 + r) * DD + bk * 32 + c;
      WT16[o] = (_Float16)v;
      WT32[o] = v;
    }
  } else {
#pragma unroll
    for (int i = 0; i < 4; ++i) {
      int r = r0 + i * 8;
      BoT[(size_t)(bn * 32 + r) * DD + bk * 32 + c] = f2bf(tile[c][r]);
    }
  }
}

// post-fixup: bid<8192 -> in-place RoPE on sq,sk; bid>=8192 -> sv transpose to svT
__global__ void k_post(u16* sq, u16* sk, const float* __restrict__ cosT,
                       const float* __restrict__ sinT, const u16* __restrict__ sv,
                       u16* __restrict__ svT) {
  __shared__ u16 tile[32][33];
  int bid = blockIdx.x;
  if (bid < 8192) {
    int i = bid * 256 + threadIdx.x;  // < 2048*16*64
    int s = i >> 10;
    int rest = i & 1023;
    int h = rest >> 6, j = rest & 63;
    size_t base = (size_t)s * DD + h * 128 + j;
    float c = cosT[(s << 6) | j], sn = sinT[(s << 6) | j];
    float a = bf2f(sq[base]), b = bf2f(sq[base + 64]);
    sq[base] = f2bf(a * c - b * sn);
    sq[base + 64] = f2bf(b * c + a * sn);
    a = bf2f(sk[base]);
    b = bf2f(sk[base + 64]);
    sk[base] = f2bf(a * c - b * sn);
    sk[base + 64] = f2bf(b * c + a * sn);
  } else {
    int b = bid - 8192;
    int bk = b & 63, bn = b >> 6;
    int c = threadIdx.x & 31, r0 = threadIdx.x >> 5;
#pragma unroll
    for (int i = 0; i < 4; ++i) {
      int r = r0 + i * 8;
      tile[r][c] = sv[(size_t)(bk * 32 + r) * DD + bn * 32 + c];
    }
    __syncthreads();
#pragma unroll
    for (int i = 0; i < 4; ++i) {
      int r = r0 + i * 8;
      svT[(size_t)(bn * 32 + r) * DD + bk * 32 + c] = tile[c][r];
    }
  }
}

// ---------------- QKV GEMM pass 1 (fp16): u ~= x16 @ W16^T ----------------
// 128x64 tiles -> 512 blocks/matrix x 3 = 1536 blocks = 6 blocks/CU (24
// waves/CU); cross-block MFMA overlap hides the 2-phase stage+barrier stall
// (m102 blocks/CU scaling, m114 mechanism). LDS 24KB dbuf; 3 GL16/step.
// Elements with |u-1| < DELTA set a byte in the transposed bytemap
// flT[mat][col][row] (aligned u32 stores). NO atomics.
__global__ __launch_bounds__(256) void k_gemm_qkv(
    const _Float16* __restrict__ xf, const _Float16* __restrict__ BqT,
    const _Float16* __restrict__ BkT, const _Float16* __restrict__ BvT, u16* __restrict__ Sq,
    u16* __restrict__ Sk, u16* __restrict__ Sv, unsigned char* __restrict__ flagT) {
  __shared__ u16 lA[2 * 4096];  // [buf][128][32]
  __shared__ u16 lB[2 * 2048];  // [buf][64][32]

  const _Float16* BT = blockIdx.y == 0 ? BqT : (blockIdx.y == 1 ? BkT : BvT);
  u16* Out = blockIdx.y == 0 ? Sq : (blockIdx.y == 1 ? Sk : Sv);
  unsigned char* flT = flagT + (size_t)blockIdx.y * 4194304;  // [col][row] bytemap

  int bid = blockIdx.x;
  int swz = (bid & 7) * 64 + (bid >> 3);  // 512 % 8 == 0, bijective XCD swizzle
  int m0 = (swz >> 5) * 128, n0 = (swz & 31) * 64;

  int tid = threadIdx.x;
  int lane = tid & 63;
  int w = tid >> 6;
  int wr = (w >> 1) * 64, wc = (w & 1) * 32;
  int l15 = lane & 15, g8 = (lane >> 4) * 8;

  int ar0 = tid >> 2, ac = (tid & 3) << 3;  // rows 0..63
  int ar1 = ar0 + 64;                        // rows 64..127

  f32x4 zero = {0.f, 0.f, 0.f, 0.f};
  f32x4 acc[4][2];
#pragma unroll
  for (int i = 0; i < 4; ++i)
#pragma unroll
    for (int j = 0; j < 2; ++j) acc[i][j] = zero;

  u16* laBase0 = lA + w * 512;
  u16* laBase1 = lA + 2048 + w * 512;
  u16* lbBase = lB + w * 512;

  auto stage = [&](int buf, int vs) {
    int k0 = vs << 5;
    GL16(&xf[(size_t)(m0 + ar0) * DD + k0 + ac], laBase0 + buf * 4096);
    GL16(&xf[(size_t)(m0 + ar1) * DD + k0 + ac], laBase1 + buf * 4096);
    GL16(&BT[(size_t)(n0 + ar0) * DD + k0 + ac], lbBase + buf * 2048);
  };

  stage(0, 0);
  __syncthreads();  // prologue: buf0 ready
  for (int vs = 0; vs < 64; ++vs) {
    int cur = vs & 1;
    if (vs + 1 < 64) stage(cur ^ 1, vs + 1);  // issue next-tile loads FIRST
    const u16* la = lA + cur * 4096;
    const u16* lb = lB + cur * 2048;
    f16x8 af[4], bfr[2];
#pragma unroll
    for (int i = 0; i < 4; ++i) af[i] = *(const f16x8*)&la[(wr + i * 16 + l15) * 32 + g8];
#pragma unroll
    for (int j = 0; j < 2; ++j) bfr[j] = *(const f16x8*)&lb[(wc + j * 16 + l15) * 32 + g8];
#pragma unroll
    for (int i = 0; i < 4; ++i)
#pragma unroll
      for (int j = 0; j < 2; ++j)
        acc[i][j] = __builtin_amdgcn_mfma_f32_16x16x32_f16(af[i], bfr[j], acc[i][j], 0, 0, 0);
    __syncthreads();  // one vmcnt(0)+barrier per tile, at the END
  }

  int g4 = (lane >> 4) * 4;
#pragma unroll
  for (int i = 0; i < 4; ++i) {
    int row0 = m0 + wr + i * 16 + g4;
#pragma unroll
    for (int j = 0; j < 2; ++j) {
      int col = n0 + wc + j * 16 + l15;
      u32 fw = 0;
#pragma unroll
      for (int r = 0; r < 4; ++r) {
        float u = acc[i][j][r];
        Out[(size_t)(row0 + r) * DD + col] = (u > 1.0f) ? (u16)0x3F80 : (u16)0;
        if (fabsf(u - 1.0f) < DELTA) fw |= (1u << (8 * r));
      }
      *(u32*)&flT[(size_t)col * 2048 + row0] = fw;  // row0 % 4 == 0, aligned
    }
  }
}

// ---------------- fixup: compact (to LDS) + exact fp32 recompute ----------
// 768 blocks; block b owns bytes [b*16384,(b+1)*16384) of flagT. Phase 1:
// build per-block worklist in LDS (no atomics, no global round-trip).
// Phase 2: each of 4 waves fixes entries i = w, w+4, ... with coalesced
// 1KB/instr dot loads.
__global__ __launch_bounds__(256) void k_fixup(
    const float* __restrict__ x, const float* __restrict__ WqT, const float* __restrict__ WkT,
    const float* __restrict__ WvT, const unsigned char* __restrict__ flagT,
    u16* __restrict__ Sq, u16* __restrict__ Sk, u16* __restrict__ Sv) {
  __shared__ u32 lw[256];
  __shared__ u32 wsum[4];
  __shared__ u32 lcnt;
  int tid = threadIdx.x;
  int lane = tid & 63;
  int w = tid >> 6;
  size_t blockBase = (size_t)blockIdx.x * 16384;
  const u32* fp = (const u32*)(flagT + blockBase);
  unsigned long long fm = 0;
#pragma unroll
  for (int it = 0; it < 4; ++it) {
    u32 m16 = 0;
#pragma unroll
    for (int wd = 0; wd < 4; ++wd) {
      u32 v = fp[it * 1024 + tid * 4 + wd];
      m16 |= (((v >> 0) & 1u) | ((v >> 7) & 2u) | ((v >> 14) & 4u) | ((v >> 21) & 8u)) << (wd * 4);
    }
    fm |= (unsigned long long)m16 << (it * 16);
  }
  u32 c = (u32)__popcll(fm);
  u32 pre = c;
#pragma unroll
  for (int d = 1; d < 64; d <<= 1) {
    u32 t = __shfl_up(pre, d, 64);
    if (lane >= d) pre += t;
  }
  if (lane == 63) wsum[w] = pre;
  __syncthreads();
  u32 wbase = 0;
#pragma unroll
  for (int i = 0; i < 4; ++i)
    if (i < w) wbase += wsum[i];
  if (tid == 0) {
    u32 tot = wsum[0] + wsum[1] + wsum[2] + wsum[3];
    lcnt = tot > 256u ? 256u : tot;
  }
  u32 pos = wbase + pre - c;  // exclusive prefix within block
  while (fm) {
    int p = __ffsll((long long)fm) - 1;
    fm &= fm - 1;
    u32 e = (u32)blockBase + (u32)(p >> 4) * 4096u + (u32)tid * 16u + (u32)(p & 15);
    if (pos < 256u) lw[pos] = e;
    ++pos;
  }
  __syncthreads();
  u32 cnt = lcnt;
  for (u32 i = w; i < cnt; i += 4) {
    u32 e = lw[i];
    int ii = (int)(e & 2047u);
    int j = (int)((e >> 11) & 2047u);
    int mat = (int)(e >> 22);
    const float* WT = mat == 0 ? WqT : (mat == 1 ? WkT : WvT);
    const float* xr = x + (size_t)ii * DD;
    const float* wrw = WT + (size_t)j * DD;
    float u = 0.f;
#pragma unroll
    for (int t = 0; t < 8; ++t) {
      float4 a = *(const float4*)&xr[t * 256 + lane * 4];
      float4 bv = *(const float4*)&wrw[t * 256 + lane * 4];
      u = fmaf(a.x, bv.x, u);
      u = fmaf(a.y, bv.y, u);
      u = fmaf(a.z, bv.z, u);
      u = fmaf(a.w, bv.w, u);
    }
#pragma unroll
    for (int sh = 32; sh; sh >>= 1) u += __shfl_xor(u, sh);
    if (lane == 0) {
      u16* Out2 = mat == 0 ? Sq : (mat == 1 ? Sk : Sv);
      Out2[(size_t)ii * DD + j] = (u > 1.0f) ? (u16)0x3F80 : (u16)0;
    }
  }
}

// ---------------- final GEMM: out_pre(bf16) @ Wo -> fp32 (128x64, 512 blk) --
__global__ __launch_bounds__(256) void k_gemm_out(const u16* __restrict__ A,
                                                  const u16* __restrict__ BT,
                                                  float* __restrict__ C) {
  __shared__ u16 lA[2 * 4096];  // [buf][128][32]
  __shared__ u16 lB[2 * 2048];  // [buf][64][32]
  int bid = blockIdx.x;
  int swz = (bid & 7) * 64 + (bid >> 3);  // 512 % 8 == 0, bijective
  int m0 = (swz >> 5) * 128, n0 = (swz & 31) * 64;
  int tid = threadIdx.x;
  int lane = tid & 63;
  int w = tid >> 6;
  int wr = (w >> 1) * 64, wc = (w & 1) * 32;
  int l15 = lane & 15, g8 = (lane >> 4) * 8;
  int ar0 = tid >> 2, ac = (tid & 3) << 3;  // rows 0..63
  int ar1 = ar0 + 64;                        // rows 64..127
  f32x4 zero = {0.f, 0.f, 0.f, 0.f};
  f32x4 acc[4][2];
#pragma unroll
  for (int i = 0; i < 4; ++i)
#pragma unroll
    for (int j = 0; j < 2; ++j) acc[i][j] = zero;

  u16* laBase0 = lA + w * 512;
  u16* laBase1 = lA + 2048 + w * 512;
  u16* lbBase = lB + w * 512;

  auto stage = [&](int buf, int vs) {
    int k0 = vs << 5;
    GL16(&A[(size_t)(m0 + ar0) * DD + k0 + ac], laBase0 + buf * 4096);
    GL16(&A[(size_t)(m0 + ar1) * DD + k0 + ac], laBase1 + buf * 4096);
    GL16(&BT[(size_t)(n0 + ar0) * DD + k0 + ac], lbBase + buf * 2048);
  };

  stage(0, 0);
  __syncthreads();
  for (int vs = 0; vs < 64; ++vs) {
    int cur = vs & 1;
    if (vs + 1 < 64) stage(cur ^ 1, vs + 1);
    const u16* la = lA + cur * 4096;
    const u16* lb = lB + cur * 2048;
    bf16x8 af[4], bfr[2];
#pragma unroll
    for (int i = 0; i < 4; ++i) af[i] = *(const bf16x8*)&la[(wr + i * 16 + l15) * 32 + g8];
#pragma unroll
    for (int j = 0; j < 2; ++j) bfr[j] = *(const bf16x8*)&lb[(wc + j * 16 + l15) * 32 + g8];
#pragma unroll
    for (int i = 0; i < 4; ++i)
#pragma unroll
      for (int j = 0; j < 2; ++j)
        acc[i][j] = __builtin_amdgcn_mfma_f32_16x16x32_bf16(af[i], bfr[j], acc[i][j], 0, 0, 0);
    __syncthreads();
  }

  int g4 = (lane >> 4) * 4;
#pragma unroll
  for (int i = 0; i < 4; ++i) {
    int row0 = m0 + wr + i * 16 + g4;
#pragma unroll
    for (int j = 0; j < 2; ++j) {
      int col = n0 + wc + j * 16 + l15;
#pragma unroll
      for (int r = 0; r < 4; ++r) C[(size_t)(row0 + r) * DD + col] = acc[i][j][r];
    }
  }
}

// ---------------- flash attention (causal), swapped QK^T ----------------
// block: 4 waves, BQ=64, BKV=64. grid: 16 heads x 32 q-blocks, heavy-first.
// T14 async-stage + T5 setprio around both MFMA clusters.
__global__ __launch_bounds__(256) void k_attn(const u16* __restrict__ rq,
                                              const u16* __restrict__ rk,
                                              const u16* __restrict__ svT,
                                              u16* __restrict__ outp) {
  __shared__ u16 lrk[64 * 136];    // [kv][d] pad 136
  __shared__ u16 lsv[128 * 72];    // [d][kv] pad 72
  __shared__ u16 lP[4 * 16 * 72];  // per-wave P [q][kv] pad 72

  int bid = blockIdx.x;
  int h = bid & 15;   // head's 32 blocks share XCD (16 % 8 == 0) -> K/V L2-local
  int i0 = bid >> 4;  // 0..31
  int qb = 31 - i0;   // heavy blocks dispatch first
  int q0 = qb * 64;

  int tid = threadIdx.x;
  int lane = tid & 63;
  int w = tid >> 6;  // 0..3
  int l15 = lane & 15;
  int g = lane >> 4;
  int qw = q0 + w * 16;
  int qpos = qw + l15;
  int pb = w * 1152 + l15 * 72;

  bf16x8 rqf[4];
#pragma unroll
  for (int ks = 0; ks < 4; ++ks)
    rqf[ks] = *(const bf16x8*)&rq[(size_t)qpos * DD + h * 128 + ks * 32 + g * 8];

  f32x4 zero = {0.f, 0.f, 0.f, 0.f};
  f32x4 acc[8];
#pragma unroll
  for (int dt = 0; dt < 8; ++dt) acc[dt] = zero;
  float mrun = -1e30f, lrun = 0.f;

  u16x8 sk_[4], sv_[4];
  auto issue = [&](int t) {
    int kv0 = t << 6;
#pragma unroll
    for (int p = 0; p < 4; ++p) {
      int idx = tid + p * 256;
      int r = idx >> 4, c8 = (idx & 15) << 3;
      sk_[p] = *(const u16x8*)&rk[(size_t)(kv0 + r) * DD + h * 128 + c8];
      int r2 = idx >> 3, d8 = (idx & 7) << 3;
      sv_[p] = *(const u16x8*)&svT[(size_t)(h * 128 + r2) * DD + kv0 + d8];
    }
  };

  int nt = (q0 >> 6) + 1;
  issue(0);
  for (int t = 0; t < nt; ++t) {
    int kv0 = t << 6;
    __syncthreads();  // prev readers done; vmcnt(0) drain -> sk_/sv_ valid
#pragma unroll
    for (int p = 0; p < 4; ++p) {
      int idx = tid + p * 256;
      int r = idx >> 4, c8 = (idx & 15) << 3;
      *(u16x8*)&lrk[r * 136 + c8] = sk_[p];
      int r2 = idx >> 3, d8 = (idx & 7) << 3;
      *(u16x8*)&lsv[r2 * 72 + d8] = sv_[p];
    }
    __syncthreads();  // LDS visible
    if (t + 1 < nt) issue(t + 1);  // in flight under the whole compute phase

    // S^T[kv][q] = rk @ rq^T
    f32x4 sacc[4];
#pragma unroll
    for (int kt = 0; kt < 4; ++kt) sacc[kt] = zero;
    __builtin_amdgcn_s_setprio(1);
#pragma unroll
    for (int kt = 0; kt < 4; ++kt)
#pragma unroll
      for (int ks = 0; ks < 4; ++ks) {
        bf16x8 a = *(const bf16x8*)&lrk[(kt * 16 + l15) * 136 + ks * 32 + g * 8];
        sacc[kt] = __builtin_amdgcn_mfma_f32_16x16x32_bf16(a, rqf[ks], sacc[kt], 0, 0, 0);
      }
    __builtin_amdgcn_s_setprio(0);
    float p[4][4];
    float mx = -1e30f;
#pragma unroll
    for (int kt = 0; kt < 4; ++kt)
#pragma unroll
      for (int rr = 0; rr < 4; ++rr) {
        int kvpos = kv0 + kt * 16 + g * 4 + rr;
        float sc = sacc[kt][rr] * SCALE_ATTN;
        sc = (kvpos <= qpos) ? sc : -1e30f;
        p[kt][rr] = sc;
        mx = fmaxf(mx, sc);
      }
    mx = fmaxf(mx, __shfl_xor(mx, 16));
    mx = fmaxf(mx, __shfl_xor(mx, 32));
    float mnew = fmaxf(mrun, mx);
    float alpha = __expf(mrun - mnew);
    float rs = 0.f;
#pragma unroll
    for (int kt = 0; kt < 4; ++kt)
#pragma unroll
      for (int rr = 0; rr < 4; ++rr) {
        float e = __expf(p[kt][rr] - mnew);
        p[kt][rr] = e;
        rs += e;
      }
    rs += __shfl_xor(rs, 16);
    rs += __shfl_xor(rs, 32);
    lrun = lrun * alpha + rs;
    mrun = mnew;
    float al[4];
#pragma unroll
    for (int rr = 0; rr < 4; ++rr) al[rr] = __shfl(alpha, (lane & 48) | (g * 4 + rr), 64);
#pragma unroll
    for (int dt = 0; dt < 8; ++dt)
#pragma unroll
      for (int rr = 0; rr < 4; ++rr) acc[dt][rr] *= al[rr];
#pragma unroll
    for (int kt = 0; kt < 4; ++kt) {
      u16x4 pk = {f2bf(p[kt][0]), f2bf(p[kt][1]), f2bf(p[kt][2]), f2bf(p[kt][3])};
      *(u16x4*)&lP[pb + kt * 16 + g * 4] = pk;
    }
    // no barrier: lP is per-wave private (same-wave ds ordering); lsv synced above.
    bf16x8 pa0 = *(const bf16x8*)&lP[pb + g * 8];
    bf16x8 pa1 = *(const bf16x8*)&lP[pb + 32 + g * 8];
    __builtin_amdgcn_s_setprio(1);
#pragma unroll
    for (int dt = 0; dt < 8; ++dt) {
      bf16x8 b0 = *(const bf16x8*)&lsv[(dt * 16 + l15) * 72 + g * 8];
      acc[dt] = __builtin_amdgcn_mfma_f32_16x16x32_bf16(pa0, b0, acc[dt], 0, 0, 0);
      bf16x8 b1 = *(const bf16x8*)&lsv[(dt * 16 + l15) * 72 + 32 + g * 8];
      acc[dt] = __builtin_amdgcn_mfma_f32_16x16x32_bf16(pa1, b1, acc[dt], 0, 0, 0);
    }
    __builtin_amdgcn_s_setprio(0);
  }

  float linv[4];
#pragma unroll
  for (int rr = 0; rr < 4; ++rr)
    linv[rr] = 1.0f / __shfl(lrun, (lane & 48) | (g * 4 + rr), 64);
#pragma unroll
  for (int dt = 0; dt < 8; ++dt)
#pragma unroll
    for (int rr = 0; rr < 4; ++rr) {
      int row = qw + g * 4 + rr;
      outp[(size_t)row * DD + h * 128 + dt * 16 + l15] = f2bf(acc[dt][rr] * linv[rr]);
    }
}

// ---------------- launcher ----------------
extern "C" void kernel_launch(void* const* d_in, const int* in_sizes, int n_in, void* d_out,
                              int out_size, void* d_ws, size_t ws_size, hipStream_t stream) {
  (void)in_sizes;
  (void)n_in;
  (void)out_size;
  const float* x = (const float*)d_in[0];
  const float* Wq = (const float*)d_in[1];
  const float* Wk = (const float*)d_in[2];
  const float* Wv = (const float*)d_in[3];
  const float* Wo = (const float*)d_in[4];
  float* out = (float*)d_out;

  const size_t SZ = (size_t)DD * DD;
  // 10 x 16-bit maps (20*SZ B) + 3 fp32 W^T (12*SZ B) + bytemap (3*SZ B) + tables.
  size_t need = 35 * SZ + 2 * (size_t)2048 * 64 * 4;
  if (ws_size < need) return;  // insufficient scratch; fail visibly without corruption

  char* p = (char*)d_ws;
  auto a2 = [&](void) {  // SZ 16-bit elems
    void* q = (void*)p;
    p += SZ * 2;
    return q;
  };
  _Float16* xf = (_Float16*)a2();
  _Float16* WqT16 = (_Float16*)a2();
  _Float16* WkT16 = (_Float16*)a2();
  _Float16* WvT16 = (_Float16*)a2();
  u16* BoT = (u16*)a2();
  u16* sq = (u16*)a2();
  u16* sk = (u16*)a2();
  u16* sv = (u16*)a2();
  u16* svT = (u16*)a2();
  u16* outp = (u16*)a2();
  float* WqT32 = (float*)p;
  p += SZ * 4;
  float* WkT32 = (float*)p;
  p += SZ * 4;
  float* WvT32 = (float*)p;
  p += SZ * 4;
  unsigned char* flagT = (unsigned char*)p;
  p += 3 * SZ;
  float* cosT = (float*)p;
  p += (size_t)2048 * 64 * 4;
  float* sinT = (float*)p;

  k_prep<<<dim3(4096, 5, 1), 256, 0, stream>>>(x, xf, cosT, sinT, Wq, Wk, Wv, Wo, WqT16, WkT16,
                                               WvT16, WqT32, WkT32, WvT32, BoT);
  k_gemm_qkv<<<dim3(512, 3, 1), 256, 0, stream>>>(xf, WqT16, WkT16, WvT16, sq, sk, sv, flagT);
  k_fixup<<<768, 256, 0, stream>>>(x, WqT32, WkT32, WvT32, flagT, sq, sk, sv);
  k_post<<<12288, 256, 0, stream>>>(sq, sk, cosT, sinT, sv, svT);
  k_attn<<<512, 256, 0, stream>>>(sq, sk, svT, outp);
  k_gemm_out<<<512, 256, 0, stream>>>(outp, BoT, out);
}

// Round 17
// 273.024 us; speedup vs baseline: 1.0891x; 1.0891x over previous
//
#include <hip/hip_runtime.h>

typedef unsigned short u16;
typedef unsigned int u32;
typedef u16 u16x4 __attribute__((ext_vector_type(4)));
typedef u16 u16x8 __attribute__((ext_vector_type(8)));
typedef float f32x4 __attribute__((ext_vector_type(4)));
typedef __bf16 bf16x8 __attribute__((ext_vector_type(8)));
typedef _Float16 f16x4 __attribute__((ext_vector_type(4)));
typedef _Float16 f16x8 __attribute__((ext_vector_type(8)));

#define DD 2048
#define SCALE_ATTN 0.08838834764831845f
#define DELTA 0.005f

// async global->LDS, 16B per lane, wave-uniform LDS base (HW: base + lane*16)
#define GL16(g, l)                                                              \
  __builtin_amdgcn_global_load_lds((const __attribute__((address_space(1))) u32*)(g), \
                                   (__attribute__((address_space(3))) u32*)(l), 16, 0, 0)

__device__ __forceinline__ u16 f2bf(float f) {
  u32 u = __float_as_uint(f);
  u32 r = (u + 0x7FFFu + ((u >> 16) & 1u)) >> 16;
  return (u16)r;
}
__device__ __forceinline__ float bf2f(u16 h) { return __uint_as_float(((u32)h) << 16); }

// ---------------- prep (single launch): y=0 cvt_x + rope tables; y=1..3
// W_{q,k,v} -> WT16 fp16 + WT32 fp32; y=4: Wo -> BoT bf16 ----------------
__global__ void k_prep(const float* __restrict__ x, _Float16* __restrict__ xf,
                       float* __restrict__ cosT, float* __restrict__ sinT,
                       const float* __restrict__ Wq, const float* __restrict__ Wk,
                       const float* __restrict__ Wv, const float* __restrict__ Wo,
                       _Float16* __restrict__ Wq16, _Float16* __restrict__ Wk16,
                       _Float16* __restrict__ Wv16, float* __restrict__ Wq32,
                       float* __restrict__ Wk32, float* __restrict__ Wv32,
                       u16* __restrict__ BoT) {
  __shared__ float tile[32][33];
  int y = blockIdx.y;
  if (y == 0) {
    int gi = blockIdx.x * 256 + threadIdx.x;
    int i = gi * 4;
    float4 v = *(const float4*)&x[i];
    f16x4 o = {(_Float16)v.x, (_Float16)v.y, (_Float16)v.z, (_Float16)v.w};
    *(f16x4*)&xf[i] = o;
    if (gi < 131072) {  // 2048*64 table entries
      int s = gi >> 6, j = gi & 63;
      float e = (float)(2 * j) / 128.0f;
      float inv = 1.0f / powf(10000.0f, e);
      float fr = (float)s * inv;
      cosT[gi] = cosf(fr);
      sinT[gi] = sinf(fr);
    }
    return;
  }
  int m = y - 1;  // 0..3
  const float* W = m == 0 ? Wq : (m == 1 ? Wk : (m == 2 ? Wv : Wo));
  int bk = blockIdx.x & 63, bn = blockIdx.x >> 6;
  int c = threadIdx.x & 31, r0 = threadIdx.x >> 5;
#pragma unroll
  for (int i = 0; i < 4; ++i) {
    int r = r0 + i * 8;
    tile[r][c] = W[(size_t)(bk * 32 + r) * DD + bn * 32 + c];
  }
  __syncthreads();
  if (m < 3) {
    _Float16* WT16 = m == 0 ? Wq16 : (m == 1 ? Wk16 : Wv16);
    float* WT32 = m == 0 ? Wq32 : (m == 1 ? Wk32 : Wv32);
#pragma unroll
    for (int i = 0; i < 4; ++i) {
      int r = r0 + i * 8;
      float v = tile[c][r];  // = W[bk*32+c][bn*32+r]
      size_t o = (size_t)(bn * 32 + r) * DD + bk * 32 + c;
      WT16[o] = (_Float16)v;
      WT32[o] = v;
    }
  } else {
#pragma unroll
    for (int i = 0; i < 4; ++i) {
      int r = r0 + i * 8;
      BoT[(size_t)(bn * 32 + r) * DD + bk * 32 + c] = f2bf(tile[c][r]);
    }
  }
}

// post-fixup: bid<8192 -> in-place RoPE on sq,sk; bid>=8192 -> sv transpose to svT
__global__ void k_post(u16* sq, u16* sk, const float* __restrict__ cosT,
                       const float* __restrict__ sinT, const u16* __restrict__ sv,
                       u16* __restrict__ svT) {
  __shared__ u16 tile[32][33];
  int bid = blockIdx.x;
  if (bid < 8192) {
    int i = bid * 256 + threadIdx.x;  // < 2048*16*64
    int s = i >> 10;
    int rest = i & 1023;
    int h = rest >> 6, j = rest & 63;
    size_t base = (size_t)s * DD + h * 128 + j;
    float c = cosT[(s << 6) | j], sn = sinT[(s << 6) | j];
    float a = bf2f(sq[base]), b = bf2f(sq[base + 64]);
    sq[base] = f2bf(a * c - b * sn);
    sq[base + 64] = f2bf(b * c + a * sn);
    a = bf2f(sk[base]);
    b = bf2f(sk[base + 64]);
    sk[base] = f2bf(a * c - b * sn);
    sk[base + 64] = f2bf(b * c + a * sn);
  } else {
    int b = bid - 8192;
    int bk = b & 63, bn = b >> 6;
    int c = threadIdx.x & 31, r0 = threadIdx.x >> 5;
#pragma unroll
    for (int i = 0; i < 4; ++i) {
      int r = r0 + i * 8;
      tile[r][c] = sv[(size_t)(bk * 32 + r) * DD + bn * 32 + c];
    }
    __syncthreads();
#pragma unroll
    for (int i = 0; i < 4; ++i) {
      int r = r0 + i * 8;
      svT[(size_t)(bn * 32 + r) * DD + bk * 32 + c] = tile[c][r];
    }
  }
}

// ---------------- QKV GEMM pass 1 (fp16): u ~= x16 @ W16^T ----------------
// 128x128 tile, 2-phase global_load_lds schedule (the measured template
// ceiling for this structure; 128x64 retile regressed -- R15 post-mortem).
__global__ __launch_bounds__(256) void k_gemm_qkv(
    const _Float16* __restrict__ xf, const _Float16* __restrict__ BqT,
    const _Float16* __restrict__ BkT, const _Float16* __restrict__ BvT, u16* __restrict__ Sq,
    u16* __restrict__ Sk, u16* __restrict__ Sv, unsigned char* __restrict__ flagT) {
  __shared__ u16 lA[2 * 4096];
  __shared__ u16 lB[2 * 4096];

  const _Float16* BT = blockIdx.y == 0 ? BqT : (blockIdx.y == 1 ? BkT : BvT);
  u16* Out = blockIdx.y == 0 ? Sq : (blockIdx.y == 1 ? Sk : Sv);
  unsigned char* flT = flagT + (size_t)blockIdx.y * 4194304;  // [col][row] bytemap

  int bid = blockIdx.x;
  int swz = (bid & 7) * 32 + (bid >> 3);  // XCD-aware swizzle, 256 % 8 == 0
  int m0 = (swz >> 4) * 128, n0 = (swz & 15) * 128;

  int tid = threadIdx.x;
  int lane = tid & 63;
  int w = tid >> 6;
  int wr = (w >> 1) * 64, wc = (w & 1) * 64;
  int l15 = lane & 15, g8 = (lane >> 4) * 8;

  int ar0 = tid >> 2, ac0 = (tid & 3) << 3;          // rows 0..63
  int ar1 = (tid + 256) >> 2, ac1 = (tid & 3) << 3;  // rows 64..127

  f32x4 zero = {0.f, 0.f, 0.f, 0.f};
  f32x4 acc[4][4];
#pragma unroll
  for (int i = 0; i < 4; ++i)
#pragma unroll
    for (int j = 0; j < 4; ++j) acc[i][j] = zero;

  u16* laBase0 = lA + w * 512;
  u16* laBase1 = lA + 2048 + w * 512;
  u16* lbBase0 = lB + w * 512;
  u16* lbBase1 = lB + 2048 + w * 512;

  auto stage = [&](int buf, int vs) {
    int k0 = vs << 5;
    int bo = buf * 4096;
    GL16(&xf[(size_t)(m0 + ar0) * DD + k0 + ac0], laBase0 + bo);
    GL16(&xf[(size_t)(m0 + ar1) * DD + k0 + ac1], laBase1 + bo);
    GL16(&BT[(size_t)(n0 + ar0) * DD + k0 + ac0], lbBase0 + bo);
    GL16(&BT[(size_t)(n0 + ar1) * DD + k0 + ac1], lbBase1 + bo);
  };

  stage(0, 0);
  __syncthreads();  // prologue: buf0 ready
  for (int vs = 0; vs < 64; ++vs) {
    int cur = vs & 1;
    if (vs + 1 < 64) stage(cur ^ 1, vs + 1);  // issue next-tile loads FIRST
    const u16* la = lA + cur * 4096;
    const u16* lb = lB + cur * 4096;
    f16x8 af[4], bfr[4];
#pragma unroll
    for (int i = 0; i < 4; ++i) af[i] = *(const f16x8*)&la[(wr + i * 16 + l15) * 32 + g8];
#pragma unroll
    for (int j = 0; j < 4; ++j) bfr[j] = *(const f16x8*)&lb[(wc + j * 16 + l15) * 32 + g8];
#pragma unroll
    for (int i = 0; i < 4; ++i)
#pragma unroll
      for (int j = 0; j < 4; ++j)
        acc[i][j] = __builtin_amdgcn_mfma_f32_16x16x32_f16(af[i], bfr[j], acc[i][j], 0, 0, 0);
    __syncthreads();  // one vmcnt(0)+barrier per tile, at the END
  }

  int g4 = (lane >> 4) * 4;
#pragma unroll
  for (int i = 0; i < 4; ++i) {
    int row0 = m0 + wr + i * 16 + g4;
#pragma unroll
    for (int j = 0; j < 4; ++j) {
      int col = n0 + wc + j * 16 + l15;
      u32 fw = 0;
#pragma unroll
      for (int r = 0; r < 4; ++r) {
        float u = acc[i][j][r];
        Out[(size_t)(row0 + r) * DD + col] = (u > 1.0f) ? (u16)0x3F80 : (u16)0;
        if (fabsf(u - 1.0f) < DELTA) fw |= (1u << (8 * r));
      }
      *(u32*)&flT[(size_t)col * 2048 + row0] = fw;  // row0 % 4 == 0, aligned
    }
  }
}

// ---------------- fixup: compact (to LDS) + exact fp32 recompute ----------
// 768 blocks; block b owns bytes [b*16384,(b+1)*16384) of flagT. Phase 1:
// build per-block worklist in LDS (no atomics, no global round-trip).
// Phase 2: each of 4 waves fixes entries i = w, w+4, ... with coalesced
// 1KB/instr dot loads.
__global__ __launch_bounds__(256) void k_fixup(
    const float* __restrict__ x, const float* __restrict__ WqT, const float* __restrict__ WkT,
    const float* __restrict__ WvT, const unsigned char* __restrict__ flagT,
    u16* __restrict__ Sq, u16* __restrict__ Sk, u16* __restrict__ Sv) {
  __shared__ u32 lw[256];
  __shared__ u32 wsum[4];
  __shared__ u32 lcnt;
  int tid = threadIdx.x;
  int lane = tid & 63;
  int w = tid >> 6;
  size_t blockBase = (size_t)blockIdx.x * 16384;
  const u32* fp = (const u32*)(flagT + blockBase);
  unsigned long long fm = 0;
#pragma unroll
  for (int it = 0; it < 4; ++it) {
    u32 m16 = 0;
#pragma unroll
    for (int wd = 0; wd < 4; ++wd) {
      u32 v = fp[it * 1024 + tid * 4 + wd];
      m16 |= (((v >> 0) & 1u) | ((v >> 7) & 2u) | ((v >> 14) & 4u) | ((v >> 21) & 8u)) << (wd * 4);
    }
    fm |= (unsigned long long)m16 << (it * 16);
  }
  u32 c = (u32)__popcll(fm);
  u32 pre = c;
#pragma unroll
  for (int d = 1; d < 64; d <<= 1) {
    u32 t = __shfl_up(pre, d, 64);
    if (lane >= d) pre += t;
  }
  if (lane == 63) wsum[w] = pre;
  __syncthreads();
  u32 wbase = 0;
#pragma unroll
  for (int i = 0; i < 4; ++i)
    if (i < w) wbase += wsum[i];
  if (tid == 0) {
    u32 tot = wsum[0] + wsum[1] + wsum[2] + wsum[3];
    lcnt = tot > 256u ? 256u : tot;
  }
  u32 pos = wbase + pre - c;  // exclusive prefix within block
  while (fm) {
    int p = __ffsll((long long)fm) - 1;
    fm &= fm - 1;
    u32 e = (u32)blockBase + (u32)(p >> 4) * 4096u + (u32)tid * 16u + (u32)(p & 15);
    if (pos < 256u) lw[pos] = e;
    ++pos;
  }
  __syncthreads();
  u32 cnt = lcnt;
  for (u32 i = w; i < cnt; i += 4) {
    u32 e = lw[i];
    int ii = (int)(e & 2047u);
    int j = (int)((e >> 11) & 2047u);
    int mat = (int)(e >> 22);
    const float* WT = mat == 0 ? WqT : (mat == 1 ? WkT : WvT);
    const float* xr = x + (size_t)ii * DD;
    const float* wrw = WT + (size_t)j * DD;
    float u = 0.f;
#pragma unroll
    for (int t = 0; t < 8; ++t) {
      float4 a = *(const float4*)&xr[t * 256 + lane * 4];
      float4 bv = *(const float4*)&wrw[t * 256 + lane * 4];
      u = fmaf(a.x, bv.x, u);
      u = fmaf(a.y, bv.y, u);
      u = fmaf(a.z, bv.z, u);
      u = fmaf(a.w, bv.w, u);
    }
#pragma unroll
    for (int sh = 32; sh; sh >>= 1) u += __shfl_xor(u, sh);
    if (lane == 0) {
      u16* Out2 = mat == 0 ? Sq : (mat == 1 ? Sk : Sv);
      Out2[(size_t)ii * DD + j] = (u > 1.0f) ? (u16)0x3F80 : (u16)0;
    }
  }
}

// ---------------- final GEMM: out_pre(bf16) @ Wo -> fp32 (128x64, 512 blk) --
__global__ __launch_bounds__(256) void k_gemm_out(const u16* __restrict__ A,
                                                  const u16* __restrict__ BT,
                                                  float* __restrict__ C) {
  __shared__ u16 lA[2 * 4096];  // [buf][128][32]
  __shared__ u16 lB[2 * 2048];  // [buf][64][32]
  int bid = blockIdx.x;
  int swz = (bid & 7) * 64 + (bid >> 3);  // 512 % 8 == 0, bijective
  int m0 = (swz >> 5) * 128, n0 = (swz & 31) * 64;
  int tid = threadIdx.x;
  int lane = tid & 63;
  int w = tid >> 6;
  int wr = (w >> 1) * 64, wc = (w & 1) * 32;
  int l15 = lane & 15, g8 = (lane >> 4) * 8;
  int ar0 = tid >> 2, ac = (tid & 3) << 3;  // rows 0..63
  int ar1 = ar0 + 64;                        // rows 64..127
  f32x4 zero = {0.f, 0.f, 0.f, 0.f};
  f32x4 acc[4][2];
#pragma unroll
  for (int i = 0; i < 4; ++i)
#pragma unroll
    for (int j = 0; j < 2; ++j) acc[i][j] = zero;

  u16* laBase0 = lA + w * 512;
  u16* laBase1 = lA + 2048 + w * 512;
  u16* lbBase = lB + w * 512;

  auto stage = [&](int buf, int vs) {
    int k0 = vs << 5;
    GL16(&A[(size_t)(m0 + ar0) * DD + k0 + ac], laBase0 + buf * 4096);
    GL16(&A[(size_t)(m0 + ar1) * DD + k0 + ac], laBase1 + buf * 4096);
    GL16(&BT[(size_t)(n0 + ar0) * DD + k0 + ac], lbBase + buf * 2048);
  };

  stage(0, 0);
  __syncthreads();
  for (int vs = 0; vs < 64; ++vs) {
    int cur = vs & 1;
    if (vs + 1 < 64) stage(cur ^ 1, vs + 1);
    const u16* la = lA + cur * 4096;
    const u16* lb = lB + cur * 2048;
    bf16x8 af[4], bfr[2];
#pragma unroll
    for (int i = 0; i < 4; ++i) af[i] = *(const bf16x8*)&la[(wr + i * 16 + l15) * 32 + g8];
#pragma unroll
    for (int j = 0; j < 2; ++j) bfr[j] = *(const bf16x8*)&lb[(wc + j * 16 + l15) * 32 + g8];
#pragma unroll
    for (int i = 0; i < 4; ++i)
#pragma unroll
      for (int j = 0; j < 2; ++j)
        acc[i][j] = __builtin_amdgcn_mfma_f32_16x16x32_bf16(af[i], bfr[j], acc[i][j], 0, 0, 0);
    __syncthreads();
  }

  int g4 = (lane >> 4) * 4;
#pragma unroll
  for (int i = 0; i < 4; ++i) {
    int row0 = m0 + wr + i * 16 + g4;
#pragma unroll
    for (int j = 0; j < 2; ++j) {
      int col = n0 + wc + j * 16 + l15;
#pragma unroll
      for (int r = 0; r < 4; ++r) C[(size_t)(row0 + r) * DD + col] = acc[i][j][r];
    }
  }
}

// ---------------- flash attention (causal), swapped QK^T ----------------
// block: 4 waves, BQ=64, BKV=64. grid: 16 heads x 32 q-blocks, heavy-first.
// T14 async-stage + T5 setprio around both MFMA clusters.
__global__ __launch_bounds__(256) void k_attn(const u16* __restrict__ rq,
                                              const u16* __restrict__ rk,
                                              const u16* __restrict__ svT,
                                              u16* __restrict__ outp) {
  __shared__ u16 lrk[64 * 136];    // [kv][d] pad 136
  __shared__ u16 lsv[128 * 72];    // [d][kv] pad 72
  __shared__ u16 lP[4 * 16 * 72];  // per-wave P [q][kv] pad 72

  int bid = blockIdx.x;
  int h = bid & 15;   // head's 32 blocks share XCD (16 % 8 == 0) -> K/V L2-local
  int i0 = bid >> 4;  // 0..31
  int qb = 31 - i0;   // heavy blocks dispatch first
  int q0 = qb * 64;

  int tid = threadIdx.x;
  int lane = tid & 63;
  int w = tid >> 6;  // 0..3
  int l15 = lane & 15;
  int g = lane >> 4;
  int qw = q0 + w * 16;
  int qpos = qw + l15;
  int pb = w * 1152 + l15 * 72;

  bf16x8 rqf[4];
#pragma unroll
  for (int ks = 0; ks < 4; ++ks)
    rqf[ks] = *(const bf16x8*)&rq[(size_t)qpos * DD + h * 128 + ks * 32 + g * 8];

  f32x4 zero = {0.f, 0.f, 0.f, 0.f};
  f32x4 acc[8];
#pragma unroll
  for (int dt = 0; dt < 8; ++dt) acc[dt] = zero;
  float mrun = -1e30f, lrun = 0.f;

  u16x8 sk_[4], sv_[4];
  auto issue = [&](int t) {
    int kv0 = t << 6;
#pragma unroll
    for (int p = 0; p < 4; ++p) {
      int idx = tid + p * 256;
      int r = idx >> 4, c8 = (idx & 15) << 3;
      sk_[p] = *(const u16x8*)&rk[(size_t)(kv0 + r) * DD + h * 128 + c8];
      int r2 = idx >> 3, d8 = (idx & 7) << 3;
      sv_[p] = *(const u16x8*)&svT[(size_t)(h * 128 + r2) * DD + kv0 + d8];
    }
  };

  int nt = (q0 >> 6) + 1;
  issue(0);
  for (int t = 0; t < nt; ++t) {
    int kv0 = t << 6;
    __syncthreads();  // prev readers done; vmcnt(0) drain -> sk_/sv_ valid
#pragma unroll
    for (int p = 0; p < 4; ++p) {
      int idx = tid + p * 256;
      int r = idx >> 4, c8 = (idx & 15) << 3;
      *(u16x8*)&lrk[r * 136 + c8] = sk_[p];
      int r2 = idx >> 3, d8 = (idx & 7) << 3;
      *(u16x8*)&lsv[r2 * 72 + d8] = sv_[p];
    }
    __syncthreads();  // LDS visible
    if (t + 1 < nt) issue(t + 1);  // in flight under the whole compute phase

    // S^T[kv][q] = rk @ rq^T
    f32x4 sacc[4];
#pragma unroll
    for (int kt = 0; kt < 4; ++kt) sacc[kt] = zero;
    __builtin_amdgcn_s_setprio(1);
#pragma unroll
    for (int kt = 0; kt < 4; ++kt)
#pragma unroll
      for (int ks = 0; ks < 4; ++ks) {
        bf16x8 a = *(const bf16x8*)&lrk[(kt * 16 + l15) * 136 + ks * 32 + g * 8];
        sacc[kt] = __builtin_amdgcn_mfma_f32_16x16x32_bf16(a, rqf[ks], sacc[kt], 0, 0, 0);
      }
    __builtin_amdgcn_s_setprio(0);
    float p[4][4];
    float mx = -1e30f;
#pragma unroll
    for (int kt = 0; kt < 4; ++kt)
#pragma unroll
      for (int rr = 0; rr < 4; ++rr) {
        int kvpos = kv0 + kt * 16 + g * 4 + rr;
        float sc = sacc[kt][rr] * SCALE_ATTN;
        sc = (kvpos <= qpos) ? sc : -1e30f;
        p[kt][rr] = sc;
        mx = fmaxf(mx, sc);
      }
    mx = fmaxf(mx, __shfl_xor(mx, 16));
    mx = fmaxf(mx, __shfl_xor(mx, 32));
    float mnew = fmaxf(mrun, mx);
    float alpha = __expf(mrun - mnew);
    float rs = 0.f;
#pragma unroll
    for (int kt = 0; kt < 4; ++kt)
#pragma unroll
      for (int rr = 0; rr < 4; ++rr) {
        float e = __expf(p[kt][rr] - mnew);
        p[kt][rr] = e;
        rs += e;
      }
    rs += __shfl_xor(rs, 16);
    rs += __shfl_xor(rs, 32);
    lrun = lrun * alpha + rs;
    mrun = mnew;
    float al[4];
#pragma unroll
    for (int rr = 0; rr < 4; ++rr) al[rr] = __shfl(alpha, (lane & 48) | (g * 4 + rr), 64);
#pragma unroll
    for (int dt = 0; dt < 8; ++dt)
#pragma unroll
      for (int rr = 0; rr < 4; ++rr) acc[dt][rr] *= al[rr];
#pragma unroll
    for (int kt = 0; kt < 4; ++kt) {
      u16x4 pk = {f2bf(p[kt][0]), f2bf(p[kt][1]), f2bf(p[kt][2]), f2bf(p[kt][3])};
      *(u16x4*)&lP[pb + kt * 16 + g * 4] = pk;
    }
    // no barrier: lP is per-wave private (same-wave ds ordering); lsv synced above.
    bf16x8 pa0 = *(const bf16x8*)&lP[pb + g * 8];
    bf16x8 pa1 = *(const bf16x8*)&lP[pb + 32 + g * 8];
    __builtin_amdgcn_s_setprio(1);
#pragma unroll
    for (int dt = 0; dt < 8; ++dt) {
      bf16x8 b0 = *(const bf16x8*)&lsv[(dt * 16 + l15) * 72 + g * 8];
      acc[dt] = __builtin_amdgcn_mfma_f32_16x16x32_bf16(pa0, b0, acc[dt], 0, 0, 0);
      bf16x8 b1 = *(const bf16x8*)&lsv[(dt * 16 + l15) * 72 + 32 + g * 8];
      acc[dt] = __builtin_amdgcn_mfma_f32_16x16x32_bf16(pa1, b1, acc[dt], 0, 0, 0);
    }
    __builtin_amdgcn_s_setprio(0);
  }

  float linv[4];
#pragma unroll
  for (int rr = 0; rr < 4; ++rr)
    linv[rr] = 1.0f / __shfl(lrun, (lane & 48) | (g * 4 + rr), 64);
#pragma unroll
  for (int dt = 0; dt < 8; ++dt)
#pragma unroll
    for (int rr = 0; rr < 4; ++rr) {
      int row = qw + g * 4 + rr;
      outp[(size_t)row * DD + h * 128 + dt * 16 + l15] = f2bf(acc[dt][rr] * linv[rr]);
    }
}

// ---------------- launcher ----------------
extern "C" void kernel_launch(void* const* d_in, const int* in_sizes, int n_in, void* d_out,
                              int out_size, void* d_ws, size_t ws_size, hipStream_t stream) {
  (void)in_sizes;
  (void)n_in;
  (void)out_size;
  const float* x = (const float*)d_in[0];
  const float* Wq = (const float*)d_in[1];
  const float* Wk = (const float*)d_in[2];
  const float* Wv = (const float*)d_in[3];
  const float* Wo = (const float*)d_in[4];
  float* out = (float*)d_out;

  const size_t SZ = (size_t)DD * DD;
  // 10 x 16-bit maps (20*SZ B) + 3 fp32 W^T (12*SZ B) + bytemap (3*SZ B) + tables.
  size_t need = 35 * SZ + 2 * (size_t)2048 * 64 * 4;
  if (ws_size < need) return;  // insufficient scratch; fail visibly without corruption

  char* p = (char*)d_ws;
  auto a2 = [&](void) {  // SZ 16-bit elems
    void* q = (void*)p;
    p += SZ * 2;
    return q;
  };
  _Float16* xf = (_Float16*)a2();
  _Float16* WqT16 = (_Float16*)a2();
  _Float16* WkT16 = (_Float16*)a2();
  _Float16* WvT16 = (_Float16*)a2();
  u16* BoT = (u16*)a2();
  u16* sq = (u16*)a2();
  u16* sk = (u16*)a2();
  u16* sv = (u16*)a2();
  u16* svT = (u16*)a2();
  u16* outp = (u16*)a2();
  float* WqT32 = (float*)p;
  p += SZ * 4;
  float* WkT32 = (float*)p;
  p += SZ * 4;
  float* WvT32 = (float*)p;
  p += SZ * 4;
  unsigned char* flagT = (unsigned char*)p;
  p += 3 * SZ;
  float* cosT = (float*)p;
  p += (size_t)2048 * 64 * 4;
  float* sinT = (float*)p;

  k_prep<<<dim3(4096, 5, 1), 256, 0, stream>>>(x, xf, cosT, sinT, Wq, Wk, Wv, Wo, WqT16, WkT16,
                                               WvT16, WqT32, WkT32, WvT32, BoT);
  k_gemm_qkv<<<dim3(256, 3, 1), 256, 0, stream>>>(xf, WqT16, WkT16, WvT16, sq, sk, sv, flagT);
  k_fixup<<<768, 256, 0, stream>>>(x, WqT32, WkT32, WvT32, flagT, sq, sk, sv);
  k_post<<<12288, 256, 0, stream>>>(sq, sk, cosT, sinT, sv, svT);
  k_attn<<<512, 256, 0, stream>>>(sq, sk, svT, outp);
  k_gemm_out<<<512, 256, 0, stream>>>(outp, BoT, out);
}